// Round 1
// baseline (630.775 us; speedup 1.0000x reference)
//
#include <hip/hip_runtime.h>
#include <hip/hip_bf16.h>
#include <hip/hip_fp16.h>

#define NN 4096

typedef __attribute__((ext_vector_type(8))) __bf16 bf16x8;
typedef __attribute__((ext_vector_type(4))) float f32x4;
typedef __attribute__((ext_vector_type(8))) _Float16 f16x8;

static __device__ __forceinline__ unsigned short f2bf_bits(float x) {
  __hip_bfloat16 h = __float2bfloat16(x);
  return __builtin_bit_cast(unsigned short, h);
}

// ---------------------------------------------------------------------------
// Kernel 1: cast outer -> bf16, and compute s[row] = sum_j outer[row][j]
// one block per row, 256 threads, float4 loads (16 KB/row)
// ---------------------------------------------------------------------------
__global__ __launch_bounds__(256) void cast_rowsum_kernel(
    const float* __restrict__ in, __hip_bfloat16* __restrict__ ob,
    float* __restrict__ s) {
  const int row = blockIdx.x;
  const int t = threadIdx.x;
  const float4* rp = (const float4*)(in + (size_t)row * NN);
  unsigned short* op = (unsigned short*)(ob + (size_t)row * NN);
  float sum = 0.f;
#pragma unroll
  for (int it = 0; it < 4; ++it) {
    const int idx = it * 256 + t;
    float4 v = rp[idx];
    sum += (v.x + v.y) + (v.z + v.w);
    ushort4 b;
    b.x = f2bf_bits(v.x);
    b.y = f2bf_bits(v.y);
    b.z = f2bf_bits(v.z);
    b.w = f2bf_bits(v.w);
    *(ushort4*)(op + idx * 4) = b;
  }
#pragma unroll
  for (int o = 32; o > 0; o >>= 1) sum += __shfl_xor(sum, o);
  __shared__ float r[4];
  if ((t & 63) == 0) r[t >> 6] = sum;
  __syncthreads();
  if (t == 0) s[row] = (r[0] + r[1]) + (r[2] + r[3]);
}

// ---------------------------------------------------------------------------
// Kernel 2: plain cast f32 -> bf16 (for W_slice, W_q)
// ---------------------------------------------------------------------------
__global__ __launch_bounds__(256) void cast_kernel(
    const float* __restrict__ in, __hip_bfloat16* __restrict__ ob) {
  const size_t idx = ((size_t)blockIdx.x * 256 + threadIdx.x) * 4;
  float4 v = *(const float4*)(in + idx);
  ushort4 b;
  b.x = f2bf_bits(v.x);
  b.y = f2bf_bits(v.y);
  b.z = f2bf_bits(v.z);
  b.w = f2bf_bits(v.w);
  *(ushort4*)((unsigned short*)ob + idx) = b;
}

// ---------------------------------------------------------------------------
// Kernel 3/4: C[i,j] = sigmoid( sum_m A[i,m]*B[j,m] + bias[bias_row?i:j] )
// m97-structure: 128x128 tile, BK=64, 4 waves (2x2), 4x4 frags of 16x16x32,
// global_load_lds width=16 staging, linear LDS, 2 barriers per K-step.
// ---------------------------------------------------------------------------
__global__ __launch_bounds__(256) void gemm_sig(
    const __hip_bfloat16* __restrict__ A, const __hip_bfloat16* __restrict__ B,
    const float* __restrict__ bias, __half* __restrict__ C, int bias_row) {
  __shared__ __hip_bfloat16 As[128 * 64];
  __shared__ __hip_bfloat16 Bs[128 * 64];

  const int tid = threadIdx.x;
  const int wid = tid >> 6;
  const int lane = tid & 63;

  const int brow = blockIdx.x * 128;
  const int bcol = blockIdx.y * 128;
  const int wr = (wid >> 1) * 64;  // wave row offset in tile
  const int wc = (wid & 1) * 64;   // wave col offset in tile

  // staging geometry: chunk = 1024 B = 8 rows x 64 bf16; lane covers 16 B
  const int srow = lane >> 3;       // 0..7
  const int scol = (lane & 7) * 8;  // 0..56

  // fragment geometry (16x16x32 bf16): lane&15 = M/N index, (lane>>4)*8 = K grp
  const int fr = lane & 15;
  const int kg = (lane >> 4) * 8;

  f32x4 acc[4][4];
#pragma unroll
  for (int m = 0; m < 4; ++m)
#pragma unroll
    for (int n = 0; n < 4; ++n) acc[m][n] = (f32x4){0.f, 0.f, 0.f, 0.f};

  for (int kt = 0; kt < NN; kt += 64) {
    __syncthreads();  // previous compute done before overwriting LDS
#pragma unroll
    for (int t = 0; t < 4; ++t) {
      const int ch = t * 4 + wid;  // 16 chunks, 4 per wave (uniform per wave)
      const int r = ch * 8 + srow;
      const __hip_bfloat16* ga = A + (size_t)(brow + r) * NN + (kt + scol);
      const __hip_bfloat16* gb = B + (size_t)(bcol + r) * NN + (kt + scol);
      __builtin_amdgcn_global_load_lds(
          (const __attribute__((address_space(1))) void*)ga,
          (__attribute__((address_space(3))) void*)(As + ch * 512), 16, 0, 0);
      __builtin_amdgcn_global_load_lds(
          (const __attribute__((address_space(1))) void*)gb,
          (__attribute__((address_space(3))) void*)(Bs + ch * 512), 16, 0, 0);
    }
    __syncthreads();  // compiler drains vmcnt before barrier -> LDS valid

#pragma unroll
    for (int kk = 0; kk < 64; kk += 32) {
      bf16x8 af[4], bfv[4];
#pragma unroll
      for (int m = 0; m < 4; ++m)
        af[m] = *(const bf16x8*)(As + (wr + m * 16 + fr) * 64 + (kk + kg));
#pragma unroll
      for (int n = 0; n < 4; ++n)
        bfv[n] = *(const bf16x8*)(Bs + (wc + n * 16 + fr) * 64 + (kk + kg));
#pragma unroll
      for (int m = 0; m < 4; ++m)
#pragma unroll
        for (int n = 0; n < 4; ++n)
          acc[m][n] = __builtin_amdgcn_mfma_f32_16x16x32_bf16(af[m], bfv[n],
                                                              acc[m][n], 0, 0, 0);
    }
  }

  // epilogue: C/D layout col=lane&15, row=(lane>>4)*4+reg (guide m89/m91)
  const int cr0 = (lane >> 4) * 4;
  const int cc = lane & 15;
#pragma unroll
  for (int m = 0; m < 4; ++m) {
#pragma unroll
    for (int n = 0; n < 4; ++n) {
#pragma unroll
      for (int j = 0; j < 4; ++j) {
        const int gi = brow + wr + m * 16 + cr0 + j;
        const int gj = bcol + wc + n * 16 + cc;
        float v = acc[m][n][j] + (bias_row ? bias[gi] : bias[gj]);
        float sg = 1.0f / (1.0f + __expf(-v));
        C[(size_t)gi * NN + gj] = __float2half(sg);
      }
    }
  }
}

// ---------------------------------------------------------------------------
// Kernel 5: out[i] = sum_j exp(q[i,j]*k[i,j]) * s[j] / sum_j exp(q[i,j]*k[i,j])
// score in (0,1) so exp needs no max-subtraction. One block per row.
// ---------------------------------------------------------------------------
__global__ __launch_bounds__(256) void softmax_out_kernel(
    const __half* __restrict__ q, const __half* __restrict__ k,
    const float* __restrict__ s, float* __restrict__ out) {
  const int i = blockIdx.x;
  const int t = threadIdx.x;
  const __half* qr = q + (size_t)i * NN;
  const __half* kr = k + (size_t)i * NN;
  float se = 0.f, ses = 0.f;
#pragma unroll
  for (int it = 0; it < 2; ++it) {
    const int j0 = (it * 256 + t) * 8;
    f16x8 qv = *(const f16x8*)(qr + j0);
    f16x8 kv = *(const f16x8*)(kr + j0);
    float4 s0 = *(const float4*)(s + j0);
    float4 s1 = *(const float4*)(s + j0 + 4);
    float sj[8] = {s0.x, s0.y, s0.z, s0.w, s1.x, s1.y, s1.z, s1.w};
#pragma unroll
    for (int u = 0; u < 8; ++u) {
      float sc = (float)qv[u] * (float)kv[u];
      float e = __expf(sc);
      se += e;
      ses += e * sj[u];
    }
  }
#pragma unroll
  for (int o = 32; o > 0; o >>= 1) {
    se += __shfl_xor(se, o);
    ses += __shfl_xor(ses, o);
  }
  __shared__ float r1[4], r2[4];
  if ((t & 63) == 0) {
    r1[t >> 6] = se;
    r2[t >> 6] = ses;
  }
  __syncthreads();
  if (t == 0)
    out[i] = ((r2[0] + r2[1]) + (r2[2] + r2[3])) /
             ((r1[0] + r1[1]) + (r1[2] + r1[3]));
}

// ---------------------------------------------------------------------------
extern "C" void kernel_launch(void* const* d_in, const int* in_sizes, int n_in,
                              void* d_out, int out_size, void* d_ws,
                              size_t ws_size, hipStream_t stream) {
  const float* outer = (const float*)d_in[0];
  const float* W_slice = (const float*)d_in[1];
  const float* b_slice = (const float*)d_in[2];
  const float* W_q = (const float*)d_in[3];
  const float* b_q = (const float*)d_in[4];
  float* out = (float*)d_out;

  char* ws = (char*)d_ws;
  const size_t MSZ = (size_t)NN * NN * 2;  // 32 MiB per N^2 16-bit matrix
  __hip_bfloat16* outer_bf = (__hip_bfloat16*)(ws);
  __hip_bfloat16* wsl_bf = (__hip_bfloat16*)(ws + MSZ);
  __hip_bfloat16* wq_bf = (__hip_bfloat16*)(ws + 2 * MSZ);
  __half* qh = (__half*)(ws + 3 * MSZ);
  __half* kh = (__half*)(ws + 4 * MSZ);
  float* s = (float*)(ws + 5 * MSZ);  // 16 KiB

  cast_rowsum_kernel<<<NN, 256, 0, stream>>>(outer, outer_bf, s);
  cast_kernel<<<NN * NN / 1024, 256, 0, stream>>>(W_slice, wsl_bf);
  cast_kernel<<<NN * NN / 1024, 256, 0, stream>>>(W_q, wq_bf);

  dim3 g(32, 32);
  // q[i,j] = sigmoid(outer@W_q^T + b_q[j])
  gemm_sig<<<g, 256, 0, stream>>>(outer_bf, wq_bf, b_q, qh, 0);
  // k[i,j] = sigmoid(W_slice@outer^T + b_slice[i])  (== sigmoid(outer@Ws^T).T)
  gemm_sig<<<g, 256, 0, stream>>>(wsl_bf, outer_bf, b_slice, kh, 1);

  softmax_out_kernel<<<NN, 256, 0, stream>>>(qh, kh, s, out);
}

// Round 2
// 500.791 us; speedup vs baseline: 1.2596x; 1.2596x over previous
//
#include <hip/hip_runtime.h>
#include <hip/hip_bf16.h>
#include <hip/hip_fp16.h>

#define NN 4096

typedef __attribute__((ext_vector_type(8))) __bf16 bf16x8;
typedef __attribute__((ext_vector_type(4))) float f32x4;
typedef __attribute__((ext_vector_type(8))) _Float16 f16x8;

static __device__ __forceinline__ unsigned short f2bf_bits(float x) {
  __hip_bfloat16 h = __float2bfloat16(x);
  return __builtin_bit_cast(unsigned short, h);
}

// ---------------------------------------------------------------------------
// Kernel 1: cast outer -> bf16, and compute s[row] = sum_j outer[row][j]
// ---------------------------------------------------------------------------
__global__ __launch_bounds__(256) void cast_rowsum_kernel(
    const float* __restrict__ in, __hip_bfloat16* __restrict__ ob,
    float* __restrict__ s) {
  const int row = blockIdx.x;
  const int t = threadIdx.x;
  const float4* rp = (const float4*)(in + (size_t)row * NN);
  unsigned short* op = (unsigned short*)(ob + (size_t)row * NN);
  float sum = 0.f;
#pragma unroll
  for (int it = 0; it < 4; ++it) {
    const int idx = it * 256 + t;
    float4 v = rp[idx];
    sum += (v.x + v.y) + (v.z + v.w);
    ushort4 b;
    b.x = f2bf_bits(v.x);
    b.y = f2bf_bits(v.y);
    b.z = f2bf_bits(v.z);
    b.w = f2bf_bits(v.w);
    *(ushort4*)(op + idx * 4) = b;
  }
#pragma unroll
  for (int o = 32; o > 0; o >>= 1) sum += __shfl_xor(sum, o);
  __shared__ float r[4];
  if ((t & 63) == 0) r[t >> 6] = sum;
  __syncthreads();
  if (t == 0) s[row] = (r[0] + r[1]) + (r[2] + r[3]);
}

// ---------------------------------------------------------------------------
// Kernel 2: plain cast f32 -> bf16
// ---------------------------------------------------------------------------
__global__ __launch_bounds__(256) void cast_kernel(
    const float* __restrict__ in, __hip_bfloat16* __restrict__ ob) {
  const size_t idx = ((size_t)blockIdx.x * 256 + threadIdx.x) * 4;
  float4 v = *(const float4*)(in + idx);
  ushort4 b;
  b.x = f2bf_bits(v.x);
  b.y = f2bf_bits(v.y);
  b.z = f2bf_bits(v.z);
  b.w = f2bf_bits(v.w);
  *(ushort4*)((unsigned short*)ob + idx) = b;
}

// ---------------------------------------------------------------------------
// GEMM: C[i,j] = sigmoid( sum_m A[i,m]*B[j,m] + bias[bias_row?i:j] )
// 256x256 tile, BK=64, 8 waves (2Mx4N), 8-phase counted-vmcnt schedule
// (T2 xor-swizzle + T3/T4 + T5 per the technique catalog).
// ---------------------------------------------------------------------------
#define BAR() asm volatile("s_barrier" ::: "memory")
#define VMW(N) asm volatile("s_waitcnt vmcnt(" #N ")" ::: "memory")
#define MFMA_(a, b, c) __builtin_amdgcn_mfma_f32_16x16x32_bf16((a), (b), (c), 0, 0, 0)
#define NOOP ((void)0)

// per-lane staging: lane covers row (lane>>3), source granule (lane&7)^(row&7)
#define STAGE_A(dbuf, g, ktE)                                                  \
  do {                                                                         \
    const int r0_ = wm * 128 + (g) * 32 + (wid & 3) * 8;                       \
    __builtin_amdgcn_global_load_lds(                                          \
        (const __attribute__((address_space(1))) void*)(Ag +                   \
            ((size_t)r0_ << 12) + (ktE) + lrowoff),                            \
        (__attribute__((address_space(3))) void*)(&As[dbuf][r0_ * 64]), 16, 0, \
        0);                                                                    \
  } while (0)

#define STAGE_B(dbuf, q, ktE)                                                  \
  do {                                                                         \
    const int r0_ = (q) * 64 + wid * 8;                                        \
    __builtin_amdgcn_global_load_lds(                                          \
        (const __attribute__((address_space(1))) void*)(Bg +                   \
            ((size_t)r0_ << 12) + (ktE) + lrowoff),                            \
        (__attribute__((address_space(3))) void*)(&Bs[dbuf][r0_ * 64]), 16, 0, \
        0);                                                                    \
  } while (0)

#define NOSA(a, b, c) ((void)0)
#define NOSB(a, b, c) ((void)0)

#define LDA8(cb, off) (*(const bf16x8*)((const char*)As[cb] + (off)))
#define LDB8(cb, off) (*(const bf16x8*)((const char*)Bs[cb] + (off)))

#define LOAD_A(cb, g)                                                          \
  af[0] = LDA8(cb, aoff0 + (2 * (g)) * 2048);                                  \
  af[1] = LDA8(cb, aoff1 + (2 * (g)) * 2048);                                  \
  af[2] = LDA8(cb, aoff0 + (2 * (g) + 1) * 2048);                              \
  af[3] = LDA8(cb, aoff1 + (2 * (g) + 1) * 2048);

#define MFMA_PH(g)                                                             \
  __builtin_amdgcn_s_setprio(1);                                               \
  acc[2 * (g)][0] = MFMA_(af[0], bfr[0][0], acc[2 * (g)][0]);                  \
  acc[2 * (g)][1] = MFMA_(af[0], bfr[1][0], acc[2 * (g)][1]);                  \
  acc[2 * (g)][2] = MFMA_(af[0], bfr[2][0], acc[2 * (g)][2]);                  \
  acc[2 * (g)][3] = MFMA_(af[0], bfr[3][0], acc[2 * (g)][3]);                  \
  acc[2 * (g) + 1][0] = MFMA_(af[2], bfr[0][0], acc[2 * (g) + 1][0]);          \
  acc[2 * (g) + 1][1] = MFMA_(af[2], bfr[1][0], acc[2 * (g) + 1][1]);          \
  acc[2 * (g) + 1][2] = MFMA_(af[2], bfr[2][0], acc[2 * (g) + 1][2]);          \
  acc[2 * (g) + 1][3] = MFMA_(af[2], bfr[3][0], acc[2 * (g) + 1][3]);          \
  acc[2 * (g)][0] = MFMA_(af[1], bfr[0][1], acc[2 * (g)][0]);                  \
  acc[2 * (g)][1] = MFMA_(af[1], bfr[1][1], acc[2 * (g)][1]);                  \
  acc[2 * (g)][2] = MFMA_(af[1], bfr[2][1], acc[2 * (g)][2]);                  \
  acc[2 * (g)][3] = MFMA_(af[1], bfr[3][1], acc[2 * (g)][3]);                  \
  acc[2 * (g) + 1][0] = MFMA_(af[3], bfr[0][1], acc[2 * (g) + 1][0]);          \
  acc[2 * (g) + 1][1] = MFMA_(af[3], bfr[1][1], acc[2 * (g) + 1][1]);          \
  acc[2 * (g) + 1][2] = MFMA_(af[3], bfr[2][1], acc[2 * (g) + 1][2]);          \
  acc[2 * (g) + 1][3] = MFMA_(af[3], bfr[3][1], acc[2 * (g) + 1][3]);          \
  __builtin_amdgcn_s_setprio(0);

// One K-tile = 4 phases. Stages: A-quad g of T+1 (kn1); B q3 of T+1 at g0;
// B q(g-1) of T+2 (kn2) at g1..3. vmcnt(6) = 3 phases x 2 issues in flight.
#define KTILE(cb, kn1, kn2, SA, SB0, SBX, W0, W1, W2, W3)                      \
  {                                                                            \
    bfr[0][0] = LDB8(cb, boff0 + 0);                                           \
    bfr[0][1] = LDB8(cb, boff1 + 0);                                           \
    bfr[1][0] = LDB8(cb, boff0 + 2048);                                        \
    bfr[1][1] = LDB8(cb, boff1 + 2048);                                        \
    bfr[2][0] = LDB8(cb, boff0 + 4096);                                        \
    bfr[2][1] = LDB8(cb, boff1 + 4096);                                        \
    bfr[3][0] = LDB8(cb, boff0 + 6144);                                        \
    bfr[3][1] = LDB8(cb, boff1 + 6144);                                        \
    LOAD_A(cb, 0);                                                             \
    SA((cb) ^ 1, 0, kn1);                                                      \
    SB0;                                                                       \
    BAR();                                                                     \
    MFMA_PH(0);                                                                \
    W0;                                                                        \
    BAR();                                                                     \
    LOAD_A(cb, 1);                                                             \
    SA((cb) ^ 1, 1, kn1);                                                      \
    SBX(cb, 0, kn2);                                                           \
    BAR();                                                                     \
    MFMA_PH(1);                                                                \
    W1;                                                                        \
    BAR();                                                                     \
    LOAD_A(cb, 2);                                                             \
    SA((cb) ^ 1, 2, kn1);                                                      \
    SBX(cb, 1, kn2);                                                           \
    BAR();                                                                     \
    MFMA_PH(2);                                                                \
    W2;                                                                        \
    BAR();                                                                     \
    LOAD_A(cb, 3);                                                             \
    SA((cb) ^ 1, 3, kn1);                                                      \
    SBX(cb, 2, kn2);                                                           \
    BAR();                                                                     \
    MFMA_PH(3);                                                                \
    W3;                                                                        \
    BAR();                                                                     \
  }

__global__ __launch_bounds__(512, 2) void gemm_sig(
    const unsigned short* __restrict__ A, const unsigned short* __restrict__ B,
    const float* __restrict__ bias, __half* __restrict__ C, int bias_row) {
  __shared__ __align__(128) unsigned short As[2][16384];
  __shared__ __align__(128) unsigned short Bs[2][16384];

  const int tid = threadIdx.x;
  const int wid = tid >> 6;
  const int lane = tid & 63;
  const int wm = wid >> 2;  // 0..1
  const int wn = wid & 3;   // 0..3

  const int brow = blockIdx.x * 256;
  const int bcol = blockIdx.y * 256;

  const unsigned short* Ag = A + (size_t)brow * NN;
  const unsigned short* Bg = B + (size_t)bcol * NN;

  // staging per-lane: row lane>>3, src granule (lane&7)^(lane>>3) (xor swizzle)
  const size_t lrowoff = (size_t)(lane >> 3) * NN + (((lane & 7) ^ (lane >> 3)) * 8);

  // compute per-lane ds_read byte offsets (xor-swizzled granule)
  const int fr = lane & 15;
  const int frlow = lane & 7;
  const int quad = lane >> 4;  // 0..3
  const int aoff0 = (wm * 128 + fr) * 128 + (((quad) ^ frlow) << 4);
  const int aoff1 = (wm * 128 + fr) * 128 + (((quad + 4) ^ frlow) << 4);
  const int boff0 = (wn * 64 + fr) * 128 + (((quad) ^ frlow) << 4);
  const int boff1 = (wn * 64 + fr) * 128 + (((quad + 4) ^ frlow) << 4);

  f32x4 acc[8][4];
#pragma unroll
  for (int m = 0; m < 8; ++m)
#pragma unroll
    for (int n = 0; n < 4; ++n) acc[m][n] = (f32x4){0.f, 0.f, 0.f, 0.f};

  bf16x8 bfr[4][2], af[4];

  // ---- prologue: 11 issues (FIFO order matters for the vmcnt ledger) ----
  STAGE_B(0, 0, 0);
  STAGE_B(0, 1, 0);
  STAGE_B(0, 2, 0);
  STAGE_B(0, 3, 0);
  STAGE_A(0, 0, 0);
  STAGE_A(0, 1, 0);
  STAGE_A(0, 2, 0);
  STAGE_A(0, 3, 0);
  STAGE_B(1, 0, 64);
  STAGE_B(1, 1, 64);
  STAGE_B(1, 2, 64);
  VMW(6);  // retires B q0-3 of T0 + A q0 of T0 (exactly phase-0's reads)
  BAR();

  // ---- main loop: K-tiles 0..61, 2 per iteration ----
  int kt = 0;
  for (int it = 0; it < 31; ++it) {
    const int k1 = kt + 64, k2 = kt + 128, k3 = kt + 192;
    KTILE(0, k1, k2, STAGE_A, STAGE_B(1, 3, k1), STAGE_B, VMW(6), VMW(6),
          VMW(6), VMW(6));
    KTILE(1, k2, k3, STAGE_A, STAGE_B(0, 3, k2), STAGE_B, VMW(6), VMW(6),
          VMW(6), VMW(6));
    kt += 128;
  }

  // ---- epilogue: K-tile 62 (stages A/Bq3 of 63, drains 6->3), K-tile 63 ----
  KTILE(0, 4032, 0, STAGE_A, STAGE_B(1, 3, 4032), NOSB, VMW(6), VMW(5), VMW(4),
        VMW(3));
  KTILE(1, 0, 0, NOSA, NOOP, NOSB, VMW(2), VMW(1), VMW(0), NOOP);

  // ---- C write: layout col=lane&15, row=(lane>>4)*4+j (m89/m91-verified) ----
  const int cr0 = (lane >> 4) * 4;
  const int cc = lane & 15;
#pragma unroll
  for (int m = 0; m < 8; ++m) {
#pragma unroll
    for (int n = 0; n < 4; ++n) {
#pragma unroll
      for (int j = 0; j < 4; ++j) {
        const int gi = brow + wm * 128 + m * 16 + cr0 + j;
        const int gj = bcol + wn * 64 + n * 16 + cc;
        float v = acc[m][n][j] + (bias_row ? bias[gi] : bias[gj]);
        C[(size_t)gi * NN + gj] = __float2half(1.0f / (1.0f + __expf(-v)));
      }
    }
  }
}

// ---------------------------------------------------------------------------
// Kernel 5: out[i] = sum_j exp(q*k)*s[j] / sum_j exp(q*k); score in (0,1)
// ---------------------------------------------------------------------------
__global__ __launch_bounds__(256) void softmax_out_kernel(
    const __half* __restrict__ q, const __half* __restrict__ k,
    const float* __restrict__ s, float* __restrict__ out) {
  const int i = blockIdx.x;
  const int t = threadIdx.x;
  const __half* qr = q + (size_t)i * NN;
  const __half* kr = k + (size_t)i * NN;
  float se = 0.f, ses = 0.f;
#pragma unroll
  for (int it = 0; it < 2; ++it) {
    const int j0 = (it * 256 + t) * 8;
    f16x8 qv = *(const f16x8*)(qr + j0);
    f16x8 kv = *(const f16x8*)(kr + j0);
    float4 s0 = *(const float4*)(s + j0);
    float4 s1 = *(const float4*)(s + j0 + 4);
    float sj[8] = {s0.x, s0.y, s0.z, s0.w, s1.x, s1.y, s1.z, s1.w};
#pragma unroll
    for (int u = 0; u < 8; ++u) {
      float sc = (float)qv[u] * (float)kv[u];
      float e = __expf(sc);
      se += e;
      ses += e * sj[u];
    }
  }
#pragma unroll
  for (int o = 32; o > 0; o >>= 1) {
    se += __shfl_xor(se, o);
    ses += __shfl_xor(ses, o);
  }
  __shared__ float r1[4], r2[4];
  if ((t & 63) == 0) {
    r1[t >> 6] = se;
    r2[t >> 6] = ses;
  }
  __syncthreads();
  if (t == 0)
    out[i] = ((r2[0] + r2[1]) + (r2[2] + r2[3])) /
             ((r1[0] + r1[1]) + (r1[2] + r1[3]));
}

// ---------------------------------------------------------------------------
extern "C" void kernel_launch(void* const* d_in, const int* in_sizes, int n_in,
                              void* d_out, int out_size, void* d_ws,
                              size_t ws_size, hipStream_t stream) {
  const float* outer = (const float*)d_in[0];
  const float* W_slice = (const float*)d_in[1];
  const float* b_slice = (const float*)d_in[2];
  const float* W_q = (const float*)d_in[3];
  const float* b_q = (const float*)d_in[4];
  float* out = (float*)d_out;

  char* ws = (char*)d_ws;
  const size_t MSZ = (size_t)NN * NN * 2;  // 32 MiB per N^2 16-bit matrix
  __hip_bfloat16* outer_bf = (__hip_bfloat16*)(ws);
  __hip_bfloat16* wsl_bf = (__hip_bfloat16*)(ws + MSZ);
  __hip_bfloat16* wq_bf = (__hip_bfloat16*)(ws + 2 * MSZ);
  __half* qh = (__half*)(ws + 3 * MSZ);
  __half* kh = (__half*)(ws + 4 * MSZ);
  float* s = (float*)(ws + 5 * MSZ);  // 16 KiB

  cast_rowsum_kernel<<<NN, 256, 0, stream>>>(outer, outer_bf, s);
  cast_kernel<<<NN * NN / 1024, 256, 0, stream>>>(W_slice, wsl_bf);
  cast_kernel<<<NN * NN / 1024, 256, 0, stream>>>(W_q, wq_bf);

  dim3 g(16, 16);
  // q[i,j] = sigmoid(outer@W_q^T + b_q[j])
  gemm_sig<<<g, 512, 0, stream>>>((const unsigned short*)outer_bf,
                                  (const unsigned short*)wq_bf, b_q, qh, 0);
  // k[i,j] = sigmoid(W_slice@outer^T + b_slice[i])
  gemm_sig<<<g, 512, 0, stream>>>((const unsigned short*)wsl_bf,
                                  (const unsigned short*)outer_bf, b_slice, kh,
                                  1);

  softmax_out_kernel<<<NN, 256, 0, stream>>>(qh, kh, s, out);
}

// Round 3
// 460.205 us; speedup vs baseline: 1.3706x; 1.0882x over previous
//
#include <hip/hip_runtime.h>
#include <hip/hip_bf16.h>
#include <hip/hip_fp16.h>

#define NN 4096

typedef __attribute__((ext_vector_type(8))) __bf16 bf16x8;
typedef __attribute__((ext_vector_type(4))) float f32x4;
typedef __attribute__((ext_vector_type(8))) _Float16 f16x8;

static __device__ __forceinline__ unsigned short f2bf_bits(float x) {
  __hip_bfloat16 h = __float2bfloat16(x);
  return __builtin_bit_cast(unsigned short, h);
}

// ---------------------------------------------------------------------------
// Kernel 1: cast outer -> bf16, and compute s[row] = sum_j outer[row][j]
// ---------------------------------------------------------------------------
__global__ __launch_bounds__(256) void cast_rowsum_kernel(
    const float* __restrict__ in, __hip_bfloat16* __restrict__ ob,
    float* __restrict__ s) {
  const int row = blockIdx.x;
  const int t = threadIdx.x;
  const float4* rp = (const float4*)(in + (size_t)row * NN);
  unsigned short* op = (unsigned short*)(ob + (size_t)row * NN);
  float sum = 0.f;
#pragma unroll
  for (int it = 0; it < 4; ++it) {
    const int idx = it * 256 + t;
    float4 v = rp[idx];
    sum += (v.x + v.y) + (v.z + v.w);
    ushort4 b;
    b.x = f2bf_bits(v.x);
    b.y = f2bf_bits(v.y);
    b.z = f2bf_bits(v.z);
    b.w = f2bf_bits(v.w);
    *(ushort4*)(op + idx * 4) = b;
  }
#pragma unroll
  for (int o = 32; o > 0; o >>= 1) sum += __shfl_xor(sum, o);
  __shared__ float r[4];
  if ((t & 63) == 0) r[t >> 6] = sum;
  __syncthreads();
  if (t == 0) s[row] = (r[0] + r[1]) + (r[2] + r[3]);
}

// ---------------------------------------------------------------------------
// Kernel 2: plain cast f32 -> bf16
// ---------------------------------------------------------------------------
__global__ __launch_bounds__(256) void cast_kernel(
    const float* __restrict__ in, __hip_bfloat16* __restrict__ ob) {
  const size_t idx = ((size_t)blockIdx.x * 256 + threadIdx.x) * 4;
  float4 v = *(const float4*)(in + idx);
  ushort4 b;
  b.x = f2bf_bits(v.x);
  b.y = f2bf_bits(v.y);
  b.z = f2bf_bits(v.z);
  b.w = f2bf_bits(v.w);
  *(ushort4*)((unsigned short*)ob + idx) = b;
}

// ---------------------------------------------------------------------------
// GEMM: C[i,j] = sigmoid( sum_m A[i,m]*B[j,m] + bias[bias_row?i:j] )
// 256x256 tile, BK=64, 8 waves (2Mx4N). 8-phase schedule with deep staging:
// vmcnt(6) ONCE per K-tile (m201/T3+T4), 5-7 phase issue-to-read depth.
// T2 xor-swizzle (both-sides), T5 setprio, T1 XCD swizzle.
// ---------------------------------------------------------------------------
#define BAR() asm volatile("s_barrier" ::: "memory")
#define VMW(N) asm volatile("s_waitcnt vmcnt(" #N ")" ::: "memory")
#define MFMA_(a, b, c) __builtin_amdgcn_mfma_f32_16x16x32_bf16((a), (b), (c), 0, 0, 0)
#define NOOP ((void)0)

// per-lane staging: lane covers row (lane>>3), source granule (lane&7)^(row&7)
#define STAGE_A(dbuf, g, ktE)                                                  \
  do {                                                                         \
    const int r0_ = wm * 128 + (g) * 32 + (wid & 3) * 8;                       \
    __builtin_amdgcn_global_load_lds(                                          \
        (const __attribute__((address_space(1))) void*)(Ag +                   \
            ((size_t)r0_ << 12) + (ktE) + lrowoff),                            \
        (__attribute__((address_space(3))) void*)(&As[dbuf][r0_ * 64]), 16, 0, \
        0);                                                                    \
  } while (0)

#define STAGE_B(dbuf, q, ktE)                                                  \
  do {                                                                         \
    const int r0_ = (q) * 64 + wid * 8;                                        \
    __builtin_amdgcn_global_load_lds(                                          \
        (const __attribute__((address_space(1))) void*)(Bg +                   \
            ((size_t)r0_ << 12) + (ktE) + lrowoff),                            \
        (__attribute__((address_space(3))) void*)(&Bs[dbuf][r0_ * 64]), 16, 0, \
        0);                                                                    \
  } while (0)

#define NOSA(a, b, c) ((void)0)
#define NOSB(a, b, c) ((void)0)

#define LDA8(cb, off) (*(const bf16x8*)((const char*)As[cb] + (off)))
#define LDB8(cb, off) (*(const bf16x8*)((const char*)Bs[cb] + (off)))

#define LOAD_A(cb, g)                                                          \
  af[0] = LDA8(cb, aoff0 + (2 * (g)) * 2048);                                  \
  af[1] = LDA8(cb, aoff1 + (2 * (g)) * 2048);                                  \
  af[2] = LDA8(cb, aoff0 + (2 * (g) + 1) * 2048);                              \
  af[3] = LDA8(cb, aoff1 + (2 * (g) + 1) * 2048);

#define MFMA_PH(g)                                                             \
  __builtin_amdgcn_s_setprio(1);                                               \
  acc[2 * (g)][0] = MFMA_(af[0], bfr[0][0], acc[2 * (g)][0]);                  \
  acc[2 * (g)][1] = MFMA_(af[0], bfr[1][0], acc[2 * (g)][1]);                  \
  acc[2 * (g)][2] = MFMA_(af[0], bfr[2][0], acc[2 * (g)][2]);                  \
  acc[2 * (g)][3] = MFMA_(af[0], bfr[3][0], acc[2 * (g)][3]);                  \
  acc[2 * (g) + 1][0] = MFMA_(af[2], bfr[0][0], acc[2 * (g) + 1][0]);          \
  acc[2 * (g) + 1][1] = MFMA_(af[2], bfr[1][0], acc[2 * (g) + 1][1]);          \
  acc[2 * (g) + 1][2] = MFMA_(af[2], bfr[2][0], acc[2 * (g) + 1][2]);          \
  acc[2 * (g) + 1][3] = MFMA_(af[2], bfr[3][0], acc[2 * (g) + 1][3]);          \
  acc[2 * (g)][0] = MFMA_(af[1], bfr[0][1], acc[2 * (g)][0]);                  \
  acc[2 * (g)][1] = MFMA_(af[1], bfr[1][1], acc[2 * (g)][1]);                  \
  acc[2 * (g)][2] = MFMA_(af[1], bfr[2][1], acc[2 * (g)][2]);                  \
  acc[2 * (g)][3] = MFMA_(af[1], bfr[3][1], acc[2 * (g)][3]);                  \
  acc[2 * (g) + 1][0] = MFMA_(af[3], bfr[0][1], acc[2 * (g) + 1][0]);          \
  acc[2 * (g) + 1][1] = MFMA_(af[3], bfr[1][1], acc[2 * (g) + 1][1]);          \
  acc[2 * (g) + 1][2] = MFMA_(af[3], bfr[2][1], acc[2 * (g) + 1][2]);          \
  acc[2 * (g) + 1][3] = MFMA_(af[3], bfr[3][1], acc[2 * (g) + 1][3]);          \
  __builtin_amdgcn_s_setprio(0);

// One K-tile (tile X, buffer cb) = 4 phases.  Staging calendar (deep):
//   ph0: A q2,q3 of X+1 (buf cb^1, regions freed by X-1 ph2/ph3)
//   ph1: B q0,q1 of X+2 (buf cb, B freed after X ph0 - B only read in ph0)
//   ph2: B q2,q3 of X+2
//   ph3: A q0,q1 of X+2 (regions freed by X ph0/ph1)
// ONE vmcnt(6) after ph3's MFMA: retires exactly through A q3(X+1) (all of
// tile X+1's data), keeps tile X+2's 6 loads in flight.  Never drains to 0
// in the main loop.
#define KTILE(cb, kn1, kn2, SA0, SBX, SA3, W)                                  \
  {                                                                            \
    bfr[0][0] = LDB8(cb, boff0 + 0);                                           \
    bfr[0][1] = LDB8(cb, boff1 + 0);                                           \
    bfr[1][0] = LDB8(cb, boff0 + 2048);                                        \
    bfr[1][1] = LDB8(cb, boff1 + 2048);                                        \
    bfr[2][0] = LDB8(cb, boff0 + 4096);                                        \
    bfr[2][1] = LDB8(cb, boff1 + 4096);                                        \
    bfr[3][0] = LDB8(cb, boff0 + 6144);                                        \
    bfr[3][1] = LDB8(cb, boff1 + 6144);                                        \
    LOAD_A(cb, 0);                                                             \
    SA0((cb) ^ 1, 2, kn1);                                                     \
    SA0((cb) ^ 1, 3, kn1);                                                     \
    BAR();                                                                     \
    MFMA_PH(0);                                                                \
    BAR();                                                                     \
    LOAD_A(cb, 1);                                                             \
    SBX(cb, 0, kn2);                                                           \
    SBX(cb, 1, kn2);                                                           \
    BAR();                                                                     \
    MFMA_PH(1);                                                                \
    BAR();                                                                     \
    LOAD_A(cb, 2);                                                             \
    SBX(cb, 2, kn2);                                                           \
    SBX(cb, 3, kn2);                                                           \
    BAR();                                                                     \
    MFMA_PH(2);                                                                \
    BAR();                                                                     \
    LOAD_A(cb, 3);                                                             \
    SA3(cb, 0, kn2);                                                           \
    SA3(cb, 1, kn2);                                                           \
    BAR();                                                                     \
    MFMA_PH(3);                                                                \
    W;                                                                         \
    BAR();                                                                     \
  }

__global__ __launch_bounds__(512, 2) void gemm_sig(
    const unsigned short* __restrict__ A, const unsigned short* __restrict__ B,
    const float* __restrict__ bias, __half* __restrict__ C, int bias_row) {
  __shared__ __align__(128) unsigned short As[2][16384];
  __shared__ __align__(128) unsigned short Bs[2][16384];

  const int tid = threadIdx.x;
  const int wid = tid >> 6;
  const int lane = tid & 63;
  const int wm = wid >> 2;  // 0..1
  const int wn = wid & 3;   // 0..3

  // T1: bijective XCD swizzle (grid 256 linear, 256%8==0). Each XCD gets a
  // 4x8 rectangle of the 16x16 tile grid -> 12 operand panels/XCD vs 18.
  const int bid = blockIdx.x;
  const int xcd = bid & 7;
  const int idx = bid >> 3;
  const int brow = ((xcd >> 1) * 4 + (idx >> 3)) * 256;
  const int bcol = ((xcd & 1) * 8 + (idx & 7)) * 256;

  const unsigned short* Ag = A + (size_t)brow * NN;
  const unsigned short* Bg = B + (size_t)bcol * NN;

  // staging per-lane: row lane>>3, src granule (lane&7)^(row&7) (xor swizzle)
  const size_t lrowoff = (size_t)(lane >> 3) * NN + (((lane & 7) ^ (lane >> 3)) * 8);

  // per-lane ds_read byte offsets (xor-swizzled granule)
  const int fr = lane & 15;
  const int frlow = lane & 7;
  const int quad = lane >> 4;  // 0..3
  const int aoff0 = (wm * 128 + fr) * 128 + (((quad) ^ frlow) << 4);
  const int aoff1 = (wm * 128 + fr) * 128 + (((quad + 4) ^ frlow) << 4);
  const int boff0 = (wn * 64 + fr) * 128 + (((quad) ^ frlow) << 4);
  const int boff1 = (wn * 64 + fr) * 128 + (((quad + 4) ^ frlow) << 4);

  f32x4 acc[8][4];
#pragma unroll
  for (int m = 0; m < 8; ++m)
#pragma unroll
    for (int n = 0; n < 4; ++n) acc[m][n] = (f32x4){0.f, 0.f, 0.f, 0.f};

  bf16x8 bfr[4][2], af[4];

  // ---- prologue: 14 issues, FIFO order matches the steady-state ledger ----
  STAGE_B(0, 0, 0);
  STAGE_B(0, 1, 0);
  STAGE_B(0, 2, 0);
  STAGE_B(0, 3, 0);
  STAGE_A(0, 0, 0);
  STAGE_A(0, 1, 0);
  STAGE_A(0, 2, 0);
  STAGE_A(0, 3, 0);
  STAGE_B(1, 0, 64);
  STAGE_B(1, 1, 64);
  STAGE_B(1, 2, 64);
  STAGE_B(1, 3, 64);
  STAGE_A(1, 0, 64);
  STAGE_A(1, 1, 64);
  VMW(6);  // retires tile0's 8 chunks; tile1's 6 stay in flight
  BAR();

  // ---- main loop: tiles 0..61 (uniform), 2 per iteration ----
  int kt = 0;
  for (int it = 0; it < 31; ++it) {
    KTILE(0, kt + 64, kt + 128, STAGE_A, STAGE_B, STAGE_A, VMW(6));
    KTILE(1, kt + 128, kt + 192, STAGE_A, STAGE_B, STAGE_A, VMW(6));
    kt += 128;
  }
  // ---- epilogue: tile 62 stages A q2,q3 of 63 then drains; tile 63 bare ----
  KTILE(0, 4032, 0, STAGE_A, NOSB, NOSA, VMW(0));
  KTILE(1, 0, 0, NOSA, NOSB, NOSA, NOOP);

  // ---- C write: layout col=lane&15, row=(lane>>4)*4+j (m89/m91-verified) ----
  const int cr0 = (lane >> 4) * 4;
  const int cc = lane & 15;
#pragma unroll
  for (int m = 0; m < 8; ++m) {
#pragma unroll
    for (int n = 0; n < 4; ++n) {
#pragma unroll
      for (int j = 0; j < 4; ++j) {
        const int gi = brow + wm * 128 + m * 16 + cr0 + j;
        const int gj = bcol + wn * 64 + n * 16 + cc;
        float v = acc[m][n][j] + (bias_row ? bias[gi] : bias[gj]);
        C[(size_t)gi * NN + gj] = __float2half(1.0f / (1.0f + __expf(-v)));
      }
    }
  }
}

// ---------------------------------------------------------------------------
// Kernel 5: out[i] = sum_j exp(q*k)*s[j] / sum_j exp(q*k); score in (0,1)
// ---------------------------------------------------------------------------
__global__ __launch_bounds__(256) void softmax_out_kernel(
    const __half* __restrict__ q, const __half* __restrict__ k,
    const float* __restrict__ s, float* __restrict__ out) {
  const int i = blockIdx.x;
  const int t = threadIdx.x;
  const __half* qr = q + (size_t)i * NN;
  const __half* kr = k + (size_t)i * NN;
  float se = 0.f, ses = 0.f;
#pragma unroll
  for (int it = 0; it < 2; ++it) {
    const int j0 = (it * 256 + t) * 8;
    f16x8 qv = *(const f16x8*)(qr + j0);
    f16x8 kv = *(const f16x8*)(kr + j0);
    float4 s0 = *(const float4*)(s + j0);
    float4 s1 = *(const float4*)(s + j0 + 4);
    float sj[8] = {s0.x, s0.y, s0.z, s0.w, s1.x, s1.y, s1.z, s1.w};
#pragma unroll
    for (int u = 0; u < 8; ++u) {
      float sc = (float)qv[u] * (float)kv[u];
      float e = __expf(sc);
      se += e;
      ses += e * sj[u];
    }
  }
#pragma unroll
  for (int o = 32; o > 0; o >>= 1) {
    se += __shfl_xor(se, o);
    ses += __shfl_xor(ses, o);
  }
  __shared__ float r1[4], r2[4];
  if ((t & 63) == 0) {
    r1[t >> 6] = se;
    r2[t >> 6] = ses;
  }
  __syncthreads();
  if (t == 0)
    out[i] = ((r2[0] + r2[1]) + (r2[2] + r2[3])) /
             ((r1[0] + r1[1]) + (r1[2] + r1[3]));
}

// ---------------------------------------------------------------------------
extern "C" void kernel_launch(void* const* d_in, const int* in_sizes, int n_in,
                              void* d_out, int out_size, void* d_ws,
                              size_t ws_size, hipStream_t stream) {
  const float* outer = (const float*)d_in[0];
  const float* W_slice = (const float*)d_in[1];
  const float* b_slice = (const float*)d_in[2];
  const float* W_q = (const float*)d_in[3];
  const float* b_q = (const float*)d_in[4];
  float* out = (float*)d_out;

  char* ws = (char*)d_ws;
  const size_t MSZ = (size_t)NN * NN * 2;  // 32 MiB per N^2 16-bit matrix
  __hip_bfloat16* outer_bf = (__hip_bfloat16*)(ws);
  __hip_bfloat16* wsl_bf = (__hip_bfloat16*)(ws + MSZ);
  __hip_bfloat16* wq_bf = (__hip_bfloat16*)(ws + 2 * MSZ);
  __half* qh = (__half*)(ws + 3 * MSZ);
  __half* kh = (__half*)(ws + 4 * MSZ);
  float* s = (float*)(ws + 5 * MSZ);  // 16 KiB

  cast_rowsum_kernel<<<NN, 256, 0, stream>>>(outer, outer_bf, s);
  cast_kernel<<<NN * NN / 1024, 256, 0, stream>>>(W_slice, wsl_bf);
  cast_kernel<<<NN * NN / 1024, 256, 0, stream>>>(W_q, wq_bf);

  // q[i,j] = sigmoid(outer@W_q^T + b_q[j])
  gemm_sig<<<256, 512, 0, stream>>>((const unsigned short*)outer_bf,
                                    (const unsigned short*)wq_bf, b_q, qh, 0);
  // k[i,j] = sigmoid(W_slice@outer^T + b_slice[i])
  gemm_sig<<<256, 512, 0, stream>>>((const unsigned short*)wsl_bf,
                                    (const unsigned short*)outer_bf, b_slice,
                                    kh, 1);

  softmax_out_kernel<<<NN, 256, 0, stream>>>(qh, kh, s, out);
}